// Round 1
// baseline (12562.118 us; speedup 1.0000x reference)
//
#include <hip/hip_runtime.h>

#define DEVFUN __device__ __forceinline__

namespace {

constexpr int kB = 128;
constexpr int kN = 512;   // N == M
constexpr int kD = 256;
constexpr int kF = 512;
constexpr int kL = 5;
constexpr float kEPS = 1e-5f;
constexpr long BND = (long)kB * kN * kD;   // 16,777,216 floats

enum Epi { EP_SIG = 0, EP_EXP, EP_MULEK, EP_RELUB, EP_BIASRES };

DEVFUN float fsig(float x) { return 1.f / (1.f + __expf(-x)); }

DEVFUN void mm16(const float (*As)[132], const float (*Bs)[132], int tx, int ty,
                 float acc[2][2][4][4]) {
#pragma unroll
  for (int k = 0; k < 16; ++k) {
    float a0[4], a1[4], b0[4], b1[4];
    *(float4*)a0 = *(const float4*)&As[k][ty * 4];
    *(float4*)a1 = *(const float4*)&As[k][ty * 4 + 64];
    *(float4*)b0 = *(const float4*)&Bs[k][tx * 4];
    *(float4*)b1 = *(const float4*)&Bs[k][tx * 4 + 64];
#pragma unroll
    for (int r = 0; r < 4; ++r) {
#pragma unroll
      for (int c = 0; c < 4; ++c) {
        acc[0][0][r][c] += a0[r] * b0[c];
        acc[0][1][r][c] += a0[r] * b1[c];
        acc[1][0][r][c] += a1[r] * b0[c];
        acc[1][1][r][c] += a1[r] * b1[c];
      }
    }
  }
}

// ----- generic X(rows x K) @ W(K x NC) with fused epilogues -----
template <int EPI>
__global__ __launch_bounds__(256) void gemm_xw(
    const float* __restrict__ X, const float* __restrict__ W, int K, int NC,
    float* __restrict__ out, int out_ld, int out_coff,
    const float* __restrict__ aux, const float* __restrict__ aux2) {
  __shared__ float As[16][132];
  __shared__ float Bs[16][132];
  const int t = threadIdx.x;
  const int tx = t & 15, ty = t >> 4;
  const long rowBase = (long)blockIdx.y * 128;
  const int colBase = blockIdx.x * 128;

  float acc[2][2][4][4];
#pragma unroll
  for (int a = 0; a < 2; ++a)
#pragma unroll
    for (int b = 0; b < 2; ++b)
#pragma unroll
      for (int r = 0; r < 4; ++r)
#pragma unroll
        for (int c = 0; c < 4; ++c) acc[a][b][r][c] = 0.f;

  for (int kt = 0; kt < K; kt += 16) {
#pragma unroll
    for (int i = 0; i < 2; ++i) {
      int f = t + i * 256;
      int r = f >> 2;
      int kq = (f & 3) << 2;
      float4 v = *(const float4*)(X + (rowBase + r) * K + (kt + kq));
      As[kq + 0][r] = v.x;
      As[kq + 1][r] = v.y;
      As[kq + 2][r] = v.z;
      As[kq + 3][r] = v.w;
    }
#pragma unroll
    for (int i = 0; i < 2; ++i) {
      int f = t + i * 256;
      int kr = f >> 5;
      int c = (f & 31) << 2;
      *(float4*)&Bs[kr][c] =
          *(const float4*)(W + (long)(kt + kr) * NC + (colBase + c));
    }
    __syncthreads();
    mm16(As, Bs, tx, ty, acc);
    __syncthreads();
  }

#pragma unroll
  for (int rh = 0; rh < 2; ++rh) {
#pragma unroll
    for (int r = 0; r < 4; ++r) {
      const long grow = rowBase + ty * 4 + rh * 64 + r;
#pragma unroll
      for (int ch = 0; ch < 2; ++ch) {
        const int gcol = colBase + tx * 4 + ch * 64;
        float4 vv;
        float* pv = reinterpret_cast<float*>(&vv);
#pragma unroll
        for (int c = 0; c < 4; ++c) pv[c] = acc[rh][ch][r][c];

        if constexpr (EPI == EP_SIG) {
#pragma unroll
          for (int c = 0; c < 4; ++c) pv[c] = fsig(pv[c]);
        } else if constexpr (EPI == EP_EXP) {
#pragma unroll
          for (int c = 0; c < 4; ++c) pv[c] = __expf(pv[c]);
        } else if constexpr (EPI == EP_MULEK) {
          const float4 ek = *(const float4*)(aux + grow * 512 + 256 + gcol);
          const float* pe = reinterpret_cast<const float*>(&ek);
#pragma unroll
          for (int c = 0; c < 4; ++c) pv[c] *= pe[c];
        } else if constexpr (EPI == EP_RELUB) {
          const float4 bb = *(const float4*)(aux + gcol);
          const float* pb = reinterpret_cast<const float*>(&bb);
#pragma unroll
          for (int c = 0; c < 4; ++c) pv[c] = fmaxf(pv[c] + pb[c], 0.f);
        } else if constexpr (EPI == EP_BIASRES) {
          const float4 bb = *(const float4*)(aux + gcol);
          const float4 rr = *(const float4*)(aux2 + grow * out_ld + gcol);
          const float* pb = reinterpret_cast<const float*>(&bb);
          const float* pr = reinterpret_cast<const float*>(&rr);
#pragma unroll
          for (int c = 0; c < 4; ++c) pv[c] = pv[c] + pb[c] + pr[c];
        }
        *(float4*)(out + grow * out_ld + out_coff + gcol) = vv;
      }
    }
  }
}

// ----- AFT GEMM: per-batch E(N x M) @ C(M x 512-slice), E computed on the fly
// den pass (NUMPASS=false): out = den buffer (B*N x 256)
// num pass (NUMPASS=true):  dst = xr + sigmoid_q * nan_to_num(num/den)
template <bool TRANS, bool NUMPASS>
__global__ __launch_bounds__(256) void gemm_aft(
    const float* __restrict__ cost, const float* __restrict__ Cbuf,
    const float* __restrict__ alpha, int aidx, const float* __restrict__ lsc,
    const float* __restrict__ den, const float* __restrict__ sq,
    const float* __restrict__ xr, float* __restrict__ out) {
  __shared__ float As[16][132];
  __shared__ float Bs[16][132];
  const int t = threadIdx.x;
  const int tx = t & 15, ty = t >> 4;
  const int b = blockIdx.z;
  const int rowBase = blockIdx.y * 128;
  const int colBase = blockIdx.x * 128;
  const float s = -alpha[aidx] * lsc[0];
  const float* A = cost + (long)b * kN * kN;
  const float* Bm = Cbuf + (long)b * kN * 512 + (NUMPASS ? 0 : 256);

  float acc[2][2][4][4];
#pragma unroll
  for (int a = 0; a < 2; ++a)
#pragma unroll
    for (int bb = 0; bb < 2; ++bb)
#pragma unroll
      for (int r = 0; r < 4; ++r)
#pragma unroll
        for (int c = 0; c < 4; ++c) acc[a][bb][r][c] = 0.f;

  for (int kt = 0; kt < kN; kt += 16) {
    if constexpr (!TRANS) {
#pragma unroll
      for (int i = 0; i < 2; ++i) {
        int f = t + i * 256;
        int r = f >> 2;
        int kq = (f & 3) << 2;
        float4 v = *(const float4*)(A + (long)(rowBase + r) * kN + kt + kq);
        As[kq + 0][r] = __expf(s * v.x);
        As[kq + 1][r] = __expf(s * v.y);
        As[kq + 2][r] = __expf(s * v.z);
        As[kq + 3][r] = __expf(s * v.w);
      }
    } else {
#pragma unroll
      for (int i = 0; i < 2; ++i) {
        int f = t + i * 256;
        int kr = f >> 5;
        int c = (f & 31) << 2;
        float4 v = *(const float4*)(A + (long)(kt + kr) * kN + rowBase + c);
        float4 e;
        e.x = __expf(s * v.x);
        e.y = __expf(s * v.y);
        e.z = __expf(s * v.z);
        e.w = __expf(s * v.w);
        *(float4*)&As[kr][c] = e;
      }
    }
#pragma unroll
    for (int i = 0; i < 2; ++i) {
      int f = t + i * 256;
      int kr = f >> 5;
      int c = (f & 31) << 2;
      *(float4*)&Bs[kr][c] =
          *(const float4*)(Bm + (long)(kt + kr) * 512 + colBase + c);
    }
    __syncthreads();
    mm16(As, Bs, tx, ty, acc);
    __syncthreads();
  }

#pragma unroll
  for (int rh = 0; rh < 2; ++rh) {
#pragma unroll
    for (int r = 0; r < 4; ++r) {
      const int lrow = rowBase + ty * 4 + rh * 64 + r;
      const long grow = (long)b * kN + lrow;
#pragma unroll
      for (int ch = 0; ch < 2; ++ch) {
        const int gcol = colBase + tx * 4 + ch * 64;
        float4 vv;
        float* pv = reinterpret_cast<float*>(&vv);
#pragma unroll
        for (int c = 0; c < 4; ++c) pv[c] = acc[rh][ch][r][c];
        if constexpr (!NUMPASS) {
          *(float4*)(out + grow * kD + gcol) = vv;
        } else {
          const float4 dd = *(const float4*)(den + grow * kD + gcol);
          const float4 ss = *(const float4*)(sq + grow * kD + gcol);
          const float4 xx = *(const float4*)(xr + grow * kD + gcol);
          const float* pd = reinterpret_cast<const float*>(&dd);
          const float* ps = reinterpret_cast<const float*>(&ss);
          const float* px = reinterpret_cast<const float*>(&xx);
#pragma unroll
          for (int c = 0; c < 4; ++c) {
            float w = pv[c] / pd[c];
            if (!(w == w)) w = 0.f;                       // NaN -> 0
            else if (w > 3.402823466e38f) w = 3.402823466e38f;
            else if (w < -3.402823466e38f) w = -3.402823466e38f;
            pv[c] = px[c] + ps[c] * w;
          }
          *(float4*)(out + grow * kD + gcol) = vv;
        }
      }
    }
  }
}

// ----- instance norm over seq (axis=1), in place, affine over channels -----
__global__ __launch_bounds__(256) void inorm(float* __restrict__ X,
                                             const float* __restrict__ g,
                                             const float* __restrict__ be) {
  const int b = blockIdx.x;
  const int ch0 = blockIdx.y * 64;
  const int t = threadIdx.x;
  const int lc = t & 63;
  const int ch = ch0 + lc;
  const int nr = t >> 6;
  const long base = (long)b * kN * kD + ch;

  float sum = 0.f, sq = 0.f;
  for (int n = nr; n < kN; n += 4) {
    float x = X[base + (long)n * kD];
    sum += x;
    sq += x * x;
  }
  __shared__ float s1[4][64], s2[4][64];
  __shared__ float mu[64], rs[64], gg[64], bb[64];
  s1[nr][lc] = sum;
  s2[nr][lc] = sq;
  __syncthreads();
  if (t < 64) {
    float ssum = s1[0][t] + s1[1][t] + s1[2][t] + s1[3][t];
    float ssq = s2[0][t] + s2[1][t] + s2[2][t] + s2[3][t];
    float m = ssum * (1.f / kN);
    float v = ssq * (1.f / kN) - m * m;
    mu[t] = m;
    rs[t] = rsqrtf(v + kEPS);
    gg[t] = g[ch0 + t];
    bb[t] = be[ch0 + t];
  }
  __syncthreads();
  const float m = mu[lc], rr = rs[lc], G = gg[lc], Bt = bb[lc];
  for (int n = nr; n < kN; n += 4) {
    long idx = base + (long)n * kD;
    X[idx] = (X[idx] - m) * rr * G + Bt;
  }
}

}  // namespace

extern "C" void kernel_launch(void* const* d_in, const int* in_sizes, int n_in,
                              void* d_out, int out_size, void* d_ws,
                              size_t ws_size, hipStream_t stream) {
  (void)in_sizes; (void)n_in; (void)out_size; (void)ws_size;

  const float* in_row = (const float*)d_in[0];
  const float* in_col = (const float*)d_in[1];
  const float* cost = (const float*)d_in[2];
  const float* lsc = (const float*)d_in[3];
  const float* Wq = (const float*)d_in[4];
  const float* Wk = (const float*)d_in[5];
  const float* Wv = (const float*)d_in[6];
  const float* g1 = (const float*)d_in[7];
  const float* be1 = (const float*)d_in[8];
  const float* W1 = (const float*)d_in[9];
  const float* b1 = (const float*)d_in[10];
  const float* W2 = (const float*)d_in[11];
  const float* b2 = (const float*)d_in[12];
  const float* g2 = (const float*)d_in[13];
  const float* be2 = (const float*)d_in[14];
  const float* alpha = (const float*)d_in[15];

  float* outRow = (float*)d_out;
  float* outCol = outRow + BND;
  float* ws = (float*)d_ws;
  float* ppRow = ws;             // BND
  float* ppCol = ppRow + BND;    // BND
  float* Cbuf = ppCol + BND;     // 2*BND  (cols 0..255 = ek*v, 256..511 = ek)
  float* denb = Cbuf + 2 * BND;  // BND
  float* qb = denb + BND;        // BND  (holds sigmoid(q))
  float* ffmid = Cbuf;           // alias: Cbuf dead after AFT GEMMs

  const dim3 blk(256);
  const dim3 gD(kD / 128, (kB * kN) / 128);   // 2 x 512
  const dim3 gF(kF / 128, (kB * kN) / 128);   // 4 x 512
  const dim3 gA(2, 4, kB);                    // AFT per-batch tiles
  const dim3 gNrm(kB, kD / 64);

  for (int l = 0; l < kL; ++l) {
    const float* srcR = (l == 0) ? in_row : ((l & 1) ? (const float*)outRow
                                                     : (const float*)ppRow);
    const float* srcC = (l == 0) ? in_col : ((l & 1) ? (const float*)outCol
                                                     : (const float*)ppCol);
    float* dstR = (l & 1) ? ppRow : outRow;
    float* dstC = (l & 1) ? ppCol : outCol;

    for (int side = 0; side < 2; ++side) {
      const float* xr = side ? srcC : srcR;
      const float* xc = side ? srcR : srcC;
      float* dst = side ? dstC : dstR;
      const int pi = l * 2 + side;
      const float* Wq_ = Wq + (long)pi * kD * kD;
      const float* Wk_ = Wk + (long)pi * kD * kD;
      const float* Wv_ = Wv + (long)pi * kD * kD;
      const float* W1_ = W1 + (long)pi * kD * kF;
      const float* b1_ = b1 + (long)pi * kF;
      const float* W2_ = W2 + (long)pi * kF * kD;
      const float* b2_ = b2 + (long)pi * kD;
      const float* g1_ = g1 + (long)pi * kD;
      const float* be1_ = be1 + (long)pi * kD;
      const float* g2_ = g2 + (long)pi * kD;
      const float* be2_ = be2 + (long)pi * kD;

      // sigmoid(xr @ Wq) -> qb
      gemm_xw<EP_SIG><<<gD, blk, 0, stream>>>(xr, Wq_, kD, kD, qb, kD, 0,
                                              nullptr, nullptr);
      // ek = exp(xc @ Wk) -> Cbuf[:, 256:512]
      gemm_xw<EP_EXP><<<gD, blk, 0, stream>>>(xc, Wk_, kD, kD, Cbuf, 512, 256,
                                              nullptr, nullptr);
      // ek*v = (xc @ Wv) * ek -> Cbuf[:, 0:256]
      gemm_xw<EP_MULEK><<<gD, blk, 0, stream>>>(xc, Wv_, kD, kD, Cbuf, 512, 0,
                                                Cbuf, nullptr);
      // den = E @ ek
      if (side == 0)
        gemm_aft<false, false><<<gA, blk, 0, stream>>>(
            cost, Cbuf, alpha, pi, lsc, nullptr, nullptr, nullptr, denb);
      else
        gemm_aft<true, false><<<gA, blk, 0, stream>>>(
            cost, Cbuf, alpha, pi, lsc, nullptr, nullptr, nullptr, denb);
      // num = E @ (ek*v); dst = xr + sig_q * nan_to_num(num/den)
      if (side == 0)
        gemm_aft<false, true><<<gA, blk, 0, stream>>>(cost, Cbuf, alpha, pi,
                                                      lsc, denb, qb, xr, dst);
      else
        gemm_aft<true, true><<<gA, blk, 0, stream>>>(cost, Cbuf, alpha, pi,
                                                     lsc, denb, qb, xr, dst);
      // h1 = instnorm(dst)
      inorm<<<gNrm, blk, 0, stream>>>(dst, g1_, be1_);
      // ffmid = relu(h1 @ W1 + b1)
      gemm_xw<EP_RELUB><<<gF, blk, 0, stream>>>(dst, W1_, kD, kF, ffmid, kF, 0,
                                                b1_, nullptr);
      // dst = ffmid @ W2 + b2 + h1   (in place residual)
      gemm_xw<EP_BIASRES><<<gD, blk, 0, stream>>>(ffmid, W2_, kF, kD, dst, kD,
                                                  0, b2_, dst);
      // out = instnorm(dst)
      inorm<<<gNrm, blk, 0, stream>>>(dst, g2_, be2_);
    }
  }
}

// Round 2
// 5301.950 us; speedup vs baseline: 2.3693x; 2.3693x over previous
//
#include <hip/hip_runtime.h>

typedef unsigned short u16;
typedef __attribute__((ext_vector_type(8))) short short8;
typedef __attribute__((ext_vector_type(4))) float f32x4;

#define DEVFUN __device__ __forceinline__

namespace {

constexpr int kB = 128;
constexpr int kN = 512;   // N == M
constexpr int kD = 256;
constexpr int kF = 512;
constexpr int kL = 5;
constexpr float kEPS = 1e-5f;
constexpr long BND = (long)kB * kN * kD;  // 16,777,216

DEVFUN float bf2f(u16 u) {
  unsigned v = ((unsigned)u) << 16;
  float f;
  __builtin_memcpy(&f, &v, 4);
  return f;
}
DEVFUN u16 f2bf(float f) {  // round-to-nearest-even
  unsigned x;
  __builtin_memcpy(&x, &f, 4);
  x = (x + 0x7FFFu + ((x >> 16) & 1u)) >> 16;
  return (u16)x;
}
DEVFUN float fsig(float x) { return 1.f / (1.f + __expf(-x)); }

union Pk8 { u16 p[8]; uint4 v; };
union Pk4 { u16 p[4]; uint2 v; };

// ---------------- transpose + fp32->bf16 : dst[z][c][r] = src[z][r][c] ----
// 64x64 tiles; LDS XOR-swizzled so both phases are bank-conflict-free.
__global__ __launch_bounds__(256) void tcvt(const float* __restrict__ src,
                                            u16* __restrict__ dst, int R,
                                            int C) {
  __shared__ u16 T[64 * 64];
  const int t = threadIdx.x;
  const long z = blockIdx.z;
  const int cBase = blockIdx.x * 64, rBase = blockIdx.y * 64;
#pragma unroll
  for (int i = 0; i < 4; ++i) {
    int u = i * 256 + t;
    int n = u >> 4, m4 = u & 15;
    float4 v = *(const float4*)(src + (z * R + rBase + n) * C + cBase + m4 * 4);
    Pk4 pk;
    pk.p[0] = f2bf(v.x); pk.p[1] = f2bf(v.y);
    pk.p[2] = f2bf(v.z); pk.p[3] = f2bf(v.w);
    int ch = (m4 >> 1) ^ ((n >> 3) & 7), hf = m4 & 1;
    *(uint2*)&T[n * 64 + ch * 8 + hf * 4] = pk.v;
  }
  __syncthreads();
#pragma unroll
  for (int j = 0; j < 2; ++j) {
    int u = j * 256 + t;
    int om = u >> 3, nc = u & 7;
    Pk8 pk;
#pragma unroll
    for (int i = 0; i < 8; ++i) {
      int n = nc * 8 + i;
      int ch = (om >> 3) ^ ((n >> 3) & 7);
      pk.p[i] = T[n * 64 + ch * 8 + (om & 7)];
    }
    *(uint4*)(dst + (z * C + cBase + om) * R + rBase + nc * 8) = pk.v;
  }
}

// --------------- shared MFMA inner step (BK=64, 128x128 tile) -------------
DEVFUN void mfma_step(const u16* As, const u16* Bs, int wr, int wc, int lr,
                      int lhi, f32x4 acc[4][4]) {
#pragma unroll
  for (int ks = 0; ks < 2; ++ks) {
    short8 af[4], bfr[4];
#pragma unroll
    for (int m = 0; m < 4; ++m) {
      int r = wr + m * 16 + lr;
      af[m] = *(const short8*)&As[r * 64 + (((ks << 2) + lhi) ^ (r & 7)) * 8];
    }
#pragma unroll
    for (int n = 0; n < 4; ++n) {
      int r = wc + n * 16 + lr;
      bfr[n] = *(const short8*)&Bs[r * 64 + (((ks << 2) + lhi) ^ (r & 7)) * 8];
    }
#pragma unroll
    for (int m = 0; m < 4; ++m)
#pragma unroll
      for (int n = 0; n < 4; ++n)
        acc[m][n] = __builtin_amdgcn_mfma_f32_16x16x32_bf16(af[m], bfr[n],
                                                            acc[m][n], 0, 0, 0);
  }
}

enum Epi { EP_SIG = 0, EP_EXPT, EP_MULEKT, EP_RELUB, EP_BIASRES };

// C[65536 x NC] = A[65536 x K] @ WT[NC x K]^T(bf16, k-contiguous rows)
template <int EPI, bool AF32>
__global__ __launch_bounds__(256) void gemm_mf(
    const void* __restrict__ Asrc, const u16* __restrict__ WT, int K, int NC,
    void* __restrict__ outp, const void* __restrict__ aux,
    const float* __restrict__ aux2) {
  (void)NC;
  __shared__ u16 As[128 * 64];
  __shared__ u16 Bs[128 * 64];
  const int t = threadIdx.x;
  const int lane = t & 63, wid = t >> 6;
  const int lr = lane & 15, lhi = lane >> 4;
  const int wr = (wid >> 1) * 64, wc = (wid & 1) * 64;
  const long rowBase = (long)blockIdx.y * 128;
  const int colBase = blockIdx.x * 128;

  f32x4 acc[4][4];
#pragma unroll
  for (int m = 0; m < 4; ++m)
#pragma unroll
    for (int n = 0; n < 4; ++n) acc[m][n] = {0.f, 0.f, 0.f, 0.f};

  for (int kt = 0; kt < K; kt += 64) {
#pragma unroll
    for (int i = 0; i < 4; ++i) {
      int u = i * 256 + t;
      int r = u >> 3, c = u & 7;
      int ch = c ^ (r & 7);
      if constexpr (AF32) {
        const float* s = (const float*)Asrc + (rowBase + r) * K + kt + c * 8;
        float4 v0 = *(const float4*)s, v1 = *(const float4*)(s + 4);
        Pk8 pk;
        pk.p[0] = f2bf(v0.x); pk.p[1] = f2bf(v0.y);
        pk.p[2] = f2bf(v0.z); pk.p[3] = f2bf(v0.w);
        pk.p[4] = f2bf(v1.x); pk.p[5] = f2bf(v1.y);
        pk.p[6] = f2bf(v1.z); pk.p[7] = f2bf(v1.w);
        *(uint4*)&As[r * 64 + ch * 8] = pk.v;
      } else {
        const u16* s = (const u16*)Asrc + (rowBase + r) * K + kt + c * 8;
        *(uint4*)&As[r * 64 + ch * 8] = *(const uint4*)s;
      }
      const u16* w = WT + (long)(colBase + r) * K + kt + c * 8;
      *(uint4*)&Bs[r * 64 + ch * 8] = *(const uint4*)w;
    }
    __syncthreads();
    mfma_step(As, Bs, wr, wc, lr, lhi, acc);
    __syncthreads();
  }

#pragma unroll
  for (int m = 0; m < 4; ++m) {
#pragma unroll
    for (int n = 0; n < 4; ++n) {
#pragma unroll
      for (int rr = 0; rr < 4; ++rr) {
        float v = acc[m][n][rr];
        long grow = rowBase + wr + m * 16 + lhi * 4 + rr;
        int gcol = colBase + wc + n * 16 + lr;
        if constexpr (EPI == EP_SIG) {
          ((u16*)outp)[grow * 256 + gcol] = f2bf(fsig(v));
        } else if constexpr (EPI == EP_EXPT) {
          long b = grow >> 9;
          int mm = (int)(grow & 511);
          ((u16*)outp)[(b * 512 + 256 + gcol) * 512 + mm] = f2bf(__expf(v));
        } else if constexpr (EPI == EP_MULEKT) {
          long b = grow >> 9;
          int mm = (int)(grow & 511);
          float ek = bf2f(((const u16*)aux)[(b * 512 + 256 + gcol) * 512 + mm]);
          ((u16*)outp)[(b * 512 + gcol) * 512 + mm] = f2bf(v * ek);
        } else if constexpr (EPI == EP_RELUB) {
          float bb = ((const float*)aux)[gcol];
          ((u16*)outp)[grow * 512 + gcol] = f2bf(fmaxf(v + bb, 0.f));
        } else {  // EP_BIASRES
          float bb = ((const float*)aux)[gcol];
          ((float*)outp)[grow * 256 + gcol] = v + bb + aux2[grow * 256 + gcol];
        }
      }
    }
  }
}

// ---- fused AFT: num & den in one kernel.  B rows 0..63 = ekv_t, 64..127 = ek_t
union SmU {
  struct { u16 A[128 * 64]; u16 B[128 * 64]; } s;
  float den[128 * 68];
};

template <bool SIDE1>
__global__ __launch_bounds__(256) void aft_mf(
    const float* __restrict__ cost, const u16* __restrict__ costT,
    const u16* __restrict__ CbufT, const float* __restrict__ alpha, int pi,
    const float* __restrict__ lsc, const u16* __restrict__ qb,
    const float* __restrict__ xr, float* __restrict__ dst) {
  __shared__ SmU sm;
  const int t = threadIdx.x;
  const int lane = t & 63, wid = t >> 6;
  const int lr = lane & 15, lhi = lane >> 4;
  const int wr = (wid >> 1) * 64, wc = (wid & 1) * 64;
  const long b = blockIdx.z;
  const int nBase = blockIdx.y * 128;
  const int dBase = blockIdx.x * 64;
  const float s = -alpha[pi] * lsc[0];

  f32x4 acc[4][4];
#pragma unroll
  for (int m = 0; m < 4; ++m)
#pragma unroll
    for (int n = 0; n < 4; ++n) acc[m][n] = {0.f, 0.f, 0.f, 0.f};

  for (int kt = 0; kt < 512; kt += 64) {
#pragma unroll
    for (int i = 0; i < 4; ++i) {
      int u = i * 256 + t;
      int r = u >> 3, c = u & 7;
      int ch = c ^ (r & 7);
      Pk8 pk;
      if constexpr (!SIDE1) {
        const float* sp = cost + (b * 512 + nBase + r) * 512 + kt + c * 8;
        float4 v0 = *(const float4*)sp, v1 = *(const float4*)(sp + 4);
        float e[8] = {v0.x, v0.y, v0.z, v0.w, v1.x, v1.y, v1.z, v1.w};
#pragma unroll
        for (int q = 0; q < 8; ++q) pk.p[q] = f2bf(__expf(s * e[q]));
      } else {
        const u16* sp = costT + (b * 512 + nBase + r) * 512 + kt + c * 8;
        Pk8 raw;
        raw.v = *(const uint4*)sp;
#pragma unroll
        for (int q = 0; q < 8; ++q) pk.p[q] = f2bf(__expf(s * bf2f(raw.p[q])));
      }
      *(uint4*)&sm.s.A[r * 64 + ch * 8] = pk.v;
      int gslot = (r < 64) ? (dBase + r) : (256 + dBase + (r - 64));
      const u16* bp = CbufT + (b * 512 + gslot) * 512 + kt + c * 8;
      *(uint4*)&sm.s.B[r * 64 + ch * 8] = *(const uint4*)bp;
    }
    __syncthreads();
    mfma_step(sm.s.A, sm.s.B, wr, wc, lr, lhi, acc);
    __syncthreads();
  }

  if (wc == 64) {  // den waves -> LDS
#pragma unroll
    for (int m = 0; m < 4; ++m)
#pragma unroll
      for (int n = 0; n < 4; ++n)
#pragma unroll
        for (int rr = 0; rr < 4; ++rr) {
          int nl = wr + m * 16 + lhi * 4 + rr;
          int dl = n * 16 + lr;
          sm.den[nl * 68 + dl] = acc[m][n][rr];
        }
  }
  __syncthreads();
  if (wc == 0) {  // num waves: combine + epilogue
#pragma unroll
    for (int m = 0; m < 4; ++m)
#pragma unroll
      for (int n = 0; n < 4; ++n)
#pragma unroll
        for (int rr = 0; rr < 4; ++rr) {
          int nl = wr + m * 16 + lhi * 4 + rr;
          int dl = n * 16 + lr;
          float dv = sm.den[nl * 68 + dl];
          float w = acc[m][n][rr] / dv;
          if (!(w == w)) w = 0.f;
          else if (w > 3.402823466e38f) w = 3.402823466e38f;
          else if (w < -3.402823466e38f) w = -3.402823466e38f;
          long grow = b * 512 + nBase + nl;
          int gcol = dBase + dl;
          float sq = bf2f(qb[grow * 256 + gcol]);
          dst[grow * 256 + gcol] = xr[grow * 256 + gcol] + sq * w;
        }
  }
}

// ----- instance norm over seq (axis=1), in place, affine over channels -----
__global__ __launch_bounds__(256) void inorm(float* __restrict__ X,
                                             const float* __restrict__ g,
                                             const float* __restrict__ be) {
  const int b = blockIdx.x;
  const int ch0 = blockIdx.y * 64;
  const int t = threadIdx.x;
  const int lc = t & 63;
  const int ch = ch0 + lc;
  const int nr = t >> 6;
  const long base = (long)b * kN * kD + ch;

  float sum = 0.f, sq = 0.f;
  for (int n = nr; n < kN; n += 4) {
    float x = X[base + (long)n * kD];
    sum += x;
    sq += x * x;
  }
  __shared__ float s1[4][64], s2[4][64];
  __shared__ float mu[64], rs[64], gg[64], bb[64];
  s1[nr][lc] = sum;
  s2[nr][lc] = sq;
  __syncthreads();
  if (t < 64) {
    float ssum = s1[0][t] + s1[1][t] + s1[2][t] + s1[3][t];
    float ssq = s2[0][t] + s2[1][t] + s2[2][t] + s2[3][t];
    float m = ssum * (1.f / kN);
    float v = ssq * (1.f / kN) - m * m;
    mu[t] = m;
    rs[t] = rsqrtf(v + kEPS);
    gg[t] = g[ch0 + t];
    bb[t] = be[ch0 + t];
  }
  __syncthreads();
  const float m = mu[lc], rr = rs[lc], G = gg[lc], Bt = bb[lc];
  for (int n = nr; n < kN; n += 4) {
    long idx = base + (long)n * kD;
    X[idx] = (X[idx] - m) * rr * G + Bt;
  }
}

}  // namespace

extern "C" void kernel_launch(void* const* d_in, const int* in_sizes, int n_in,
                              void* d_out, int out_size, void* d_ws,
                              size_t ws_size, hipStream_t stream) {
  (void)in_sizes; (void)n_in; (void)out_size; (void)ws_size;

  const float* in_row = (const float*)d_in[0];
  const float* in_col = (const float*)d_in[1];
  const float* cost = (const float*)d_in[2];
  const float* lsc = (const float*)d_in[3];
  const float* Wq = (const float*)d_in[4];
  const float* Wk = (const float*)d_in[5];
  const float* Wv = (const float*)d_in[6];
  const float* g1 = (const float*)d_in[7];
  const float* be1 = (const float*)d_in[8];
  const float* W1 = (const float*)d_in[9];
  const float* b1 = (const float*)d_in[10];
  const float* W2 = (const float*)d_in[11];
  const float* b2 = (const float*)d_in[12];
  const float* g2 = (const float*)d_in[13];
  const float* be2 = (const float*)d_in[14];
  const float* alpha = (const float*)d_in[15];

  float* outRow = (float*)d_out;
  float* outCol = outRow + BND;
  float* ppRow = (float*)d_ws;          // BND f32
  float* ppCol = ppRow + BND;           // BND f32
  u16* qb = (u16*)(ppCol + BND);        // BND bf16: sigmoid(q)
  u16* CbufT = qb + BND;                // 2*BND bf16: [b][d]ekv_t | [b][256+d]ek_t
  u16* ffmid = CbufT;                   // alias (dead after AFT)
  u16* WqT = CbufT + 2 * BND;
  u16* WkT = WqT + 10L * 256 * 256;
  u16* WvT = WkT + 10L * 256 * 256;
  u16* W1T = WvT + 10L * 256 * 256;     // [pi][f=512][d=256]
  u16* W2T = W1T + 10L * 512 * 256;     // [pi][d=256][f=512]
  u16* costT = W2T + 10L * 256 * 512;   // [b][m][n] bf16

  const dim3 blk(256);
  // one-time prep (re-run every call: deterministic)
  tcvt<<<dim3(4, 4, 10), blk, 0, stream>>>(Wq, WqT, 256, 256);
  tcvt<<<dim3(4, 4, 10), blk, 0, stream>>>(Wk, WkT, 256, 256);
  tcvt<<<dim3(4, 4, 10), blk, 0, stream>>>(Wv, WvT, 256, 256);
  tcvt<<<dim3(8, 4, 10), blk, 0, stream>>>(W1, W1T, 256, 512);
  tcvt<<<dim3(4, 8, 10), blk, 0, stream>>>(W2, W2T, 512, 256);
  tcvt<<<dim3(8, 8, 128), blk, 0, stream>>>(cost, costT, 512, 512);

  const dim3 gD(2, 512), gF(4, 512), gA(4, 4, 128), gNrm(128, 4);

  for (int l = 0; l < kL; ++l) {
    const float* srcR = (l == 0) ? in_row
                                 : ((l & 1) ? (const float*)outRow
                                            : (const float*)ppRow);
    const float* srcC = (l == 0) ? in_col
                                 : ((l & 1) ? (const float*)outCol
                                            : (const float*)ppCol);
    float* dstR = (l & 1) ? ppRow : outRow;
    float* dstC = (l & 1) ? ppCol : outCol;

    for (int side = 0; side < 2; ++side) {
      const float* xr = side ? srcC : srcR;
      const float* xc = side ? srcR : srcC;
      float* dst = side ? dstC : dstR;
      const int pi = l * 2 + side;

      gemm_mf<EP_SIG, true><<<gD, blk, 0, stream>>>(
          xr, WqT + (long)pi * 256 * 256, 256, 256, qb, nullptr, nullptr);
      gemm_mf<EP_EXPT, true><<<gD, blk, 0, stream>>>(
          xc, WkT + (long)pi * 256 * 256, 256, 256, CbufT, nullptr, nullptr);
      gemm_mf<EP_MULEKT, true><<<gD, blk, 0, stream>>>(
          xc, WvT + (long)pi * 256 * 256, 256, 256, CbufT, CbufT, nullptr);
      if (side == 0)
        aft_mf<false><<<gA, blk, 0, stream>>>(cost, costT, CbufT, alpha, pi,
                                              lsc, qb, xr, dst);
      else
        aft_mf<true><<<gA, blk, 0, stream>>>(cost, costT, CbufT, alpha, pi,
                                             lsc, qb, xr, dst);
      inorm<<<gNrm, blk, 0, stream>>>(dst, g1 + pi * 256, be1 + pi * 256);
      gemm_mf<EP_RELUB, true><<<gF, blk, 0, stream>>>(
          dst, W1T + (long)pi * 512 * 256, 256, 512, ffmid, b1 + pi * 512,
          nullptr);
      gemm_mf<EP_BIASRES, false><<<gD, blk, 0, stream>>>(
          ffmid, W2T + (long)pi * 256 * 512, 512, 256, dst, b2 + pi * 256,
          dst);
      inorm<<<gNrm, blk, 0, stream>>>(dst, g2 + pi * 256, be2 + pi * 256);
    }
  }
}

// Round 3
// 5139.669 us; speedup vs baseline: 2.4441x; 1.0316x over previous
//
#include <hip/hip_runtime.h>

typedef unsigned short u16;
typedef __attribute__((ext_vector_type(8))) short short8;
typedef __attribute__((ext_vector_type(4))) float f32x4;

#define DEVFUN __device__ __forceinline__

namespace {

constexpr int kB = 128;
constexpr int kN = 512;   // N == M
constexpr int kD = 256;
constexpr int kF = 512;
constexpr int kL = 5;
constexpr float kEPS = 1e-5f;
constexpr long BND = (long)kB * kN * kD;  // 16,777,216

DEVFUN float bf2f(u16 u) {
  unsigned v = ((unsigned)u) << 16;
  float f;
  __builtin_memcpy(&f, &v, 4);
  return f;
}
DEVFUN u16 f2bf(float f) {  // round-to-nearest-even
  unsigned x;
  __builtin_memcpy(&x, &f, 4);
  x = (x + 0x7FFFu + ((x >> 16) & 1u)) >> 16;
  return (u16)x;
}
DEVFUN float fsig(float x) { return 1.f / (1.f + __expf(-x)); }

union Pk8 { u16 p[8]; uint4 v; };
union Pk4 { u16 p[4]; uint2 v; };

// ---------------- transpose (+optional exp) fp32->bf16 -------------------
// dst[z][c][r] = f(src[z][r][c]); 64x64 tiles, XOR-swizzled LDS.
template <bool EXP>
__global__ __launch_bounds__(256) void tcvt(const float* __restrict__ src,
                                            u16* __restrict__ dst, int R,
                                            int C, const float* __restrict__ al,
                                            int pi, const float* __restrict__ ls) {
  __shared__ u16 T[64 * 64];
  const int t = threadIdx.x;
  const long z = blockIdx.z;
  const int cBase = blockIdx.x * 64, rBase = blockIdx.y * 64;
  float s = 0.f;
  if constexpr (EXP) s = -al[pi] * ls[0];
#pragma unroll
  for (int i = 0; i < 4; ++i) {
    int u = i * 256 + t;
    int n = u >> 4, m4 = u & 15;
    float4 v = *(const float4*)(src + (z * R + rBase + n) * C + cBase + m4 * 4);
    Pk4 pk;
    if constexpr (EXP) {
      pk.p[0] = f2bf(__expf(s * v.x)); pk.p[1] = f2bf(__expf(s * v.y));
      pk.p[2] = f2bf(__expf(s * v.z)); pk.p[3] = f2bf(__expf(s * v.w));
    } else {
      pk.p[0] = f2bf(v.x); pk.p[1] = f2bf(v.y);
      pk.p[2] = f2bf(v.z); pk.p[3] = f2bf(v.w);
    }
    int ch = (m4 >> 1) ^ ((n >> 3) & 7), hf = m4 & 1;
    *(uint2*)&T[n * 64 + ch * 8 + hf * 4] = pk.v;
  }
  __syncthreads();
#pragma unroll
  for (int j = 0; j < 2; ++j) {
    int u = j * 256 + t;
    int om = u >> 3, nc = u & 7;
    Pk8 pk;
#pragma unroll
    for (int i = 0; i < 8; ++i) {
      int n = nc * 8 + i;
      int ch = (om >> 3) ^ ((n >> 3) & 7);
      pk.p[i] = T[n * 64 + ch * 8 + (om & 7)];
    }
    *(uint4*)(dst + (z * C + cBase + om) * R + rBase + nc * 8) = pk.v;
  }
}

// ------------- elementwise exp: E[i] = bf16(exp(s*cost[i])) --------------
__global__ __launch_bounds__(256) void eexp(const float* __restrict__ src,
                                            u16* __restrict__ dst, long n8,
                                            const float* __restrict__ al,
                                            int pi, const float* __restrict__ ls) {
  const float s = -al[pi] * ls[0];
  for (long i = blockIdx.x * 256 + threadIdx.x; i < n8;
       i += (long)gridDim.x * 256) {
    const float* p = src + i * 8;
    float4 v0 = *(const float4*)p, v1 = *(const float4*)(p + 4);
    Pk8 pk;
    pk.p[0] = f2bf(__expf(s * v0.x)); pk.p[1] = f2bf(__expf(s * v0.y));
    pk.p[2] = f2bf(__expf(s * v0.z)); pk.p[3] = f2bf(__expf(s * v0.w));
    pk.p[4] = f2bf(__expf(s * v1.x)); pk.p[5] = f2bf(__expf(s * v1.y));
    pk.p[6] = f2bf(__expf(s * v1.z)); pk.p[7] = f2bf(__expf(s * v1.w));
    *(uint4*)(dst + i * 8) = pk.v;
  }
}

// ------------- elementwise fp32 -> bf16 ----------------------------------
__global__ __launch_bounds__(256) void cvtb(const float* __restrict__ src,
                                            u16* __restrict__ dst, long n8) {
  for (long i = blockIdx.x * 256 + threadIdx.x; i < n8;
       i += (long)gridDim.x * 256) {
    const float* p = src + i * 8;
    float4 v0 = *(const float4*)p, v1 = *(const float4*)(p + 4);
    Pk8 pk;
    pk.p[0] = f2bf(v0.x); pk.p[1] = f2bf(v0.y);
    pk.p[2] = f2bf(v0.z); pk.p[3] = f2bf(v0.w);
    pk.p[4] = f2bf(v1.x); pk.p[5] = f2bf(v1.y);
    pk.p[6] = f2bf(v1.z); pk.p[7] = f2bf(v1.w);
    *(uint4*)(dst + i * 8) = pk.v;
  }
}

// --------------- shared MFMA inner step (BK=64, 128x128 tile) -------------
DEVFUN void mfma_step(const u16* As, const u16* Bs, int wr, int wc, int lr,
                      int lhi, f32x4 acc[4][4]) {
#pragma unroll
  for (int ks = 0; ks < 2; ++ks) {
    short8 af[4], bfr[4];
#pragma unroll
    for (int m = 0; m < 4; ++m) {
      int r = wr + m * 16 + lr;
      af[m] = *(const short8*)&As[r * 64 + (((ks << 2) + lhi) ^ (r & 7)) * 8];
    }
#pragma unroll
    for (int n = 0; n < 4; ++n) {
      int r = wc + n * 16 + lr;
      bfr[n] = *(const short8*)&Bs[r * 64 + (((ks << 2) + lhi) ^ (r & 7)) * 8];
    }
#pragma unroll
    for (int m = 0; m < 4; ++m)
#pragma unroll
      for (int n = 0; n < 4; ++n)
        acc[m][n] = __builtin_amdgcn_mfma_f32_16x16x32_bf16(af[m], bfr[n],
                                                            acc[m][n], 0, 0, 0);
  }
}

enum Epi { EP_SIG = 0, EP_EXPT, EP_MULEKT, EP_RELUB, EP_BIASRES };

// C[65536 x NC] = A[65536 x K](bf16) @ WT[NC x K]^T(bf16), XCD-swizzled grid
template <int EPI>
__global__ __launch_bounds__(256) void gemm_mf(
    const u16* __restrict__ Asrc, const u16* __restrict__ WT, int K, int gx,
    void* __restrict__ outp, const void* __restrict__ aux,
    const float* __restrict__ aux2) {
  __shared__ u16 As[128 * 64];
  __shared__ u16 Bs[128 * 64];
  const int t = threadIdx.x;
  const int lane = t & 63, wid = t >> 6;
  const int lr = lane & 15, lhi = lane >> 4;
  const int wr = (wid >> 1) * 64, wc = (wid & 1) * 64;
  const int cpx = gridDim.x >> 3;
  const int rb = (blockIdx.x & 7) * cpx + (blockIdx.x >> 3);
  const int bx = rb % gx;
  const long rowBase = (long)(rb / gx) * 128;
  const int colBase = bx * 128;

  f32x4 acc[4][4];
#pragma unroll
  for (int m = 0; m < 4; ++m)
#pragma unroll
    for (int n = 0; n < 4; ++n) acc[m][n] = {0.f, 0.f, 0.f, 0.f};

  for (int kt = 0; kt < K; kt += 64) {
#pragma unroll
    for (int i = 0; i < 4; ++i) {
      int u = i * 256 + t;
      int r = u >> 3, c = u & 7;
      int ch = c ^ (r & 7);
      const u16* s = Asrc + (rowBase + r) * K + kt + c * 8;
      *(uint4*)&As[r * 64 + ch * 8] = *(const uint4*)s;
      const u16* w = WT + (long)(colBase + r) * K + kt + c * 8;
      *(uint4*)&Bs[r * 64 + ch * 8] = *(const uint4*)w;
    }
    __syncthreads();
    mfma_step(As, Bs, wr, wc, lr, lhi, acc);
    __syncthreads();
  }

#pragma unroll
  for (int m = 0; m < 4; ++m) {
#pragma unroll
    for (int n = 0; n < 4; ++n) {
#pragma unroll
      for (int rr = 0; rr < 4; ++rr) {
        float v = acc[m][n][rr];
        long grow = rowBase + wr + m * 16 + lhi * 4 + rr;
        int gcol = colBase + wc + n * 16 + lr;
        if constexpr (EPI == EP_SIG) {
          ((u16*)outp)[grow * 256 + gcol] = f2bf(fsig(v));
        } else if constexpr (EPI == EP_EXPT) {
          long b = grow >> 9;
          int mm = (int)(grow & 511);
          ((u16*)outp)[(b * 512 + 256 + gcol) * 512 + mm] = f2bf(__expf(v));
        } else if constexpr (EPI == EP_MULEKT) {
          long b = grow >> 9;
          int mm = (int)(grow & 511);
          float ek = bf2f(((const u16*)aux)[(b * 512 + 256 + gcol) * 512 + mm]);
          ((u16*)outp)[(b * 512 + gcol) * 512 + mm] = f2bf(v * ek);
        } else if constexpr (EPI == EP_RELUB) {
          float bb = ((const float*)aux)[gcol];
          ((u16*)outp)[grow * 512 + gcol] = f2bf(fmaxf(v + bb, 0.f));
        } else {  // EP_BIASRES
          float bb = ((const float*)aux)[gcol];
          ((float*)outp)[grow * 256 + gcol] = v + bb + aux2[grow * 256 + gcol];
        }
      }
    }
  }
}

// ---- fused AFT: num & den.  B rows 0..63 = ekv_t, 64..127 = ek_t ----
union SmU {
  struct { u16 A[128 * 64]; u16 B[128 * 64]; } s;
  float den[128 * 68];
};

__global__ __launch_bounds__(256) void aft_mf(
    const u16* __restrict__ Ebuf, const u16* __restrict__ CbufT,
    const u16* __restrict__ qb, const float* __restrict__ xr,
    float* __restrict__ dst) {
  __shared__ SmU sm;
  const int t = threadIdx.x;
  const int lane = t & 63, wid = t >> 6;
  const int lr = lane & 15, lhi = lane >> 4;
  const int wr = (wid >> 1) * 64, wc = (wid & 1) * 64;
  // XCD-chunked swizzle: each batch's 16 tiles pinned to one XCD
  const int rb = (blockIdx.x & 7) * 256 + (blockIdx.x >> 3);
  const long b = rb >> 4;
  const int nBase = ((rb >> 2) & 3) * 128;
  const int dBase = (rb & 3) * 64;

  f32x4 acc[4][4];
#pragma unroll
  for (int m = 0; m < 4; ++m)
#pragma unroll
    for (int n = 0; n < 4; ++n) acc[m][n] = {0.f, 0.f, 0.f, 0.f};

  for (int kt = 0; kt < 512; kt += 64) {
#pragma unroll
    for (int i = 0; i < 4; ++i) {
      int u = i * 256 + t;
      int r = u >> 3, c = u & 7;
      int ch = c ^ (r & 7);
      const u16* ap = Ebuf + (b * 512 + nBase + r) * 512 + kt + c * 8;
      *(uint4*)&sm.s.A[r * 64 + ch * 8] = *(const uint4*)ap;
      int gslot = (r < 64) ? (dBase + r) : (256 + dBase + (r - 64));
      const u16* bp = CbufT + (b * 512 + gslot) * 512 + kt + c * 8;
      *(uint4*)&sm.s.B[r * 64 + ch * 8] = *(const uint4*)bp;
    }
    __syncthreads();
    mfma_step(sm.s.A, sm.s.B, wr, wc, lr, lhi, acc);
    __syncthreads();
  }

  if (wc == 64) {  // den waves -> LDS
#pragma unroll
    for (int m = 0; m < 4; ++m)
#pragma unroll
      for (int n = 0; n < 4; ++n)
#pragma unroll
        for (int rr = 0; rr < 4; ++rr) {
          int nl = wr + m * 16 + lhi * 4 + rr;
          int dl = n * 16 + lr;
          sm.den[nl * 68 + dl] = acc[m][n][rr];
        }
  }
  __syncthreads();
  if (wc == 0) {  // num waves: combine + epilogue
#pragma unroll
    for (int m = 0; m < 4; ++m)
#pragma unroll
      for (int n = 0; n < 4; ++n)
#pragma unroll
        for (int rr = 0; rr < 4; ++rr) {
          int nl = wr + m * 16 + lhi * 4 + rr;
          int dl = n * 16 + lr;
          float dv = sm.den[nl * 68 + dl];
          float w = acc[m][n][rr] / dv;
          if (!(w == w)) w = 0.f;
          else if (w > 3.402823466e38f) w = 3.402823466e38f;
          else if (w < -3.402823466e38f) w = -3.402823466e38f;
          long grow = b * 512 + nBase + nl;
          int gcol = dBase + dl;
          float sq = bf2f(qb[grow * 256 + gcol]);
          dst[grow * 256 + gcol] = xr[grow * 256 + gcol] + sq * w;
        }
  }
}

// ----- instance norm over seq; in-place fp32 + bf16 copy -----------------
__global__ __launch_bounds__(256) void inorm(float* __restrict__ X,
                                             const float* __restrict__ g,
                                             const float* __restrict__ be,
                                             u16* __restrict__ Xb) {
  const int b = blockIdx.x;
  const int ch0 = blockIdx.y * 64;
  const int t = threadIdx.x;
  const int lc = t & 63;
  const int ch = ch0 + lc;
  const int nr = t >> 6;
  const long base = (long)b * kN * kD + ch;

  float sum = 0.f, sq = 0.f;
  for (int n = nr; n < kN; n += 4) {
    float x = X[base + (long)n * kD];
    sum += x;
    sq += x * x;
  }
  __shared__ float s1[4][64], s2[4][64];
  __shared__ float mu[64], rs[64], gg[64], bb[64];
  s1[nr][lc] = sum;
  s2[nr][lc] = sq;
  __syncthreads();
  if (t < 64) {
    float ssum = s1[0][t] + s1[1][t] + s1[2][t] + s1[3][t];
    float ssq = s2[0][t] + s2[1][t] + s2[2][t] + s2[3][t];
    float m = ssum * (1.f / kN);
    float v = ssq * (1.f / kN) - m * m;
    mu[t] = m;
    rs[t] = rsqrtf(v + kEPS);
    gg[t] = g[ch0 + t];
    bb[t] = be[ch0 + t];
  }
  __syncthreads();
  const float m = mu[lc], rr = rs[lc], G = gg[lc], Bt = bb[lc];
  for (int n = nr; n < kN; n += 4) {
    long idx = base + (long)n * kD;
    float y = (X[idx] - m) * rr * G + Bt;
    X[idx] = y;
    Xb[idx] = f2bf(y);
  }
}

}  // namespace

extern "C" void kernel_launch(void* const* d_in, const int* in_sizes, int n_in,
                              void* d_out, int out_size, void* d_ws,
                              size_t ws_size, hipStream_t stream) {
  (void)in_sizes; (void)n_in; (void)out_size; (void)ws_size;

  const float* in_row = (const float*)d_in[0];
  const float* in_col = (const float*)d_in[1];
  const float* cost = (const float*)d_in[2];
  const float* lsc = (const float*)d_in[3];
  const float* Wq = (const float*)d_in[4];
  const float* Wk = (const float*)d_in[5];
  const float* Wv = (const float*)d_in[6];
  const float* g1 = (const float*)d_in[7];
  const float* be1 = (const float*)d_in[8];
  const float* W1 = (const float*)d_in[9];
  const float* b1 = (const float*)d_in[10];
  const float* W2 = (const float*)d_in[11];
  const float* b2 = (const float*)d_in[12];
  const float* g2 = (const float*)d_in[13];
  const float* be2 = (const float*)d_in[14];
  const float* alpha = (const float*)d_in[15];

  float* outRow = (float*)d_out;
  float* outCol = outRow + BND;
  float* ppRow = (float*)d_ws;          // BND f32
  float* ppCol = ppRow + BND;           // BND f32
  u16* qb = (u16*)(ppCol + BND);        // BND bf16 (sigmoid q; aliased as h1b)
  u16* h1b = qb;
  u16* CbufT = qb + BND;                // 2*BND bf16
  u16* ffmid = CbufT;                   // alias (dead after AFT)
  u16* Ebuf = CbufT + 2 * BND;          // 2*BND bf16: exp(s*cost) per side
  u16* bSt = Ebuf + 2 * BND;            // 4*BND bf16 states [parity][side]
  u16* WqT = bSt + 4 * BND;
  u16* WkT = WqT + 10L * 256 * 256;
  u16* WvT = WkT + 10L * 256 * 256;
  u16* W1T = WvT + 10L * 256 * 256;     // [pi][f=512][d=256]
  u16* W2T = W1T + 10L * 512 * 256;     // [pi][d=256][f=512]

  const dim3 blk(256);
  // one-time prep
  tcvt<false><<<dim3(4, 4, 10), blk, 0, stream>>>(Wq, WqT, 256, 256, nullptr, 0, nullptr);
  tcvt<false><<<dim3(4, 4, 10), blk, 0, stream>>>(Wk, WkT, 256, 256, nullptr, 0, nullptr);
  tcvt<false><<<dim3(4, 4, 10), blk, 0, stream>>>(Wv, WvT, 256, 256, nullptr, 0, nullptr);
  tcvt<false><<<dim3(8, 4, 10), blk, 0, stream>>>(W1, W1T, 256, 512, nullptr, 0, nullptr);
  tcvt<false><<<dim3(4, 8, 10), blk, 0, stream>>>(W2, W2T, 512, 256, nullptr, 0, nullptr);
  cvtb<<<1024, blk, 0, stream>>>(in_row, bSt + 0 * BND, BND / 8);
  cvtb<<<1024, blk, 0, stream>>>(in_col, bSt + 1 * BND, BND / 8);

  for (int l = 0; l < kL; ++l) {
    const int inPar = l & 1, outPar = 1 - inPar;
    const float* srcR = (l == 0) ? in_row
                                 : (inPar ? (const float*)outRow
                                          : (const float*)ppRow);
    const float* srcC = (l == 0) ? in_col
                                 : (inPar ? (const float*)outCol
                                          : (const float*)ppCol);
    float* dstR = inPar ? ppRow : outRow;
    float* dstC = inPar ? ppCol : outCol;
    const u16* bR = bSt + (inPar * 2 + 0) * BND;
    const u16* bC = bSt + (inPar * 2 + 1) * BND;

    for (int side = 0; side < 2; ++side) {
      const float* xr = side ? srcC : srcR;
      const u16* xrB = side ? bC : bR;
      const u16* xcB = side ? bR : bC;
      float* dst = side ? dstC : dstR;
      u16* outB = bSt + (outPar * 2 + side) * BND;
      const int pi = l * 2 + side;

      // E = bf16(exp(-alpha*lsc * cost)), oriented for this side's rows
      if (side == 0)
        eexp<<<4096, blk, 0, stream>>>(cost, Ebuf, (long)kB * 512 * 512 / 8,
                                       alpha, pi, lsc);
      else
        tcvt<true><<<dim3(8, 8, 128), blk, 0, stream>>>(cost, Ebuf, 512, 512,
                                                        alpha, pi, lsc);

      gemm_mf<EP_SIG><<<1024, blk, 0, stream>>>(
          xrB, WqT + (long)pi * 256 * 256, 256, 2, qb, nullptr, nullptr);
      gemm_mf<EP_EXPT><<<1024, blk, 0, stream>>>(
          xcB, WkT + (long)pi * 256 * 256, 256, 2, CbufT, nullptr, nullptr);
      gemm_mf<EP_MULEKT><<<1024, blk, 0, stream>>>(
          xcB, WvT + (long)pi * 256 * 256, 256, 2, CbufT, CbufT, nullptr);
      aft_mf<<<2048, blk, 0, stream>>>(Ebuf, CbufT, qb, xr, dst);
      inorm<<<dim3(128, 4), blk, 0, stream>>>(dst, g1 + pi * 256,
                                              be1 + pi * 256, h1b);
      gemm_mf<EP_RELUB><<<2048, blk, 0, stream>>>(
          h1b, W1T + (long)pi * 512 * 256, 256, 4, ffmid, b1 + pi * 512,
          nullptr);
      gemm_mf<EP_BIASRES><<<1024, blk, 0, stream>>>(
          ffmid, W2T + (long)pi * 256 * 512, 512, 2, dst, b2 + pi * 256, dst);
      inorm<<<dim3(128, 4), blk, 0, stream>>>(dst, g2 + pi * 256,
                                              be2 + pi * 256, outB);
    }
  }
}

// Round 4
// 5048.179 us; speedup vs baseline: 2.4884x; 1.0181x over previous
//
#include <hip/hip_runtime.h>

typedef unsigned short u16;
typedef __attribute__((ext_vector_type(8))) short short8;
typedef __attribute__((ext_vector_type(4))) float f32x4;

#define DEVFUN __device__ __forceinline__

namespace {

constexpr int kB = 128;
constexpr int kN = 512;   // N == M
constexpr int kD = 256;
constexpr int kF = 512;
constexpr int kL = 5;
constexpr float kEPS = 1e-5f;
constexpr long BND = (long)kB * kN * kD;  // 16,777,216

DEVFUN float bf2f(u16 u) {
  unsigned v = ((unsigned)u) << 16;
  float f;
  __builtin_memcpy(&f, &v, 4);
  return f;
}
DEVFUN u16 f2bf(float f) {  // round-to-nearest-even
  unsigned x;
  __builtin_memcpy(&x, &f, 4);
  x = (x + 0x7FFFu + ((x >> 16) & 1u)) >> 16;
  return (u16)x;
}
DEVFUN float fsig(float x) { return 1.f / (1.f + __expf(-x)); }

union Pk8 { u16 p[8]; uint4 v; };
union Pk4 { u16 p[4]; uint2 v; };

// async global->LDS, 16B per lane; LDS dest wave-uniform base + lane*16
DEVFUN void gload16(const u16* g, u16* l) {
  __builtin_amdgcn_global_load_lds(
      (const __attribute__((address_space(1))) void*)g,
      (__attribute__((address_space(3))) void*)l, 16, 0, 0);
}

// ---------------- transpose (+optional exp) fp32->bf16 -------------------
template <bool EXP>
__global__ __launch_bounds__(256) void tcvt(const float* __restrict__ src,
                                            u16* __restrict__ dst, int R,
                                            int C, const float* __restrict__ al,
                                            int pi, const float* __restrict__ ls) {
  __shared__ u16 T[64 * 64];
  const int t = threadIdx.x;
  const long z = blockIdx.z;
  const int cBase = blockIdx.x * 64, rBase = blockIdx.y * 64;
  float s = 0.f;
  if constexpr (EXP) s = -al[pi] * ls[0];
#pragma unroll
  for (int i = 0; i < 4; ++i) {
    int u = i * 256 + t;
    int n = u >> 4, m4 = u & 15;
    float4 v = *(const float4*)(src + (z * R + rBase + n) * C + cBase + m4 * 4);
    Pk4 pk;
    if constexpr (EXP) {
      pk.p[0] = f2bf(__expf(s * v.x)); pk.p[1] = f2bf(__expf(s * v.y));
      pk.p[2] = f2bf(__expf(s * v.z)); pk.p[3] = f2bf(__expf(s * v.w));
    } else {
      pk.p[0] = f2bf(v.x); pk.p[1] = f2bf(v.y);
      pk.p[2] = f2bf(v.z); pk.p[3] = f2bf(v.w);
    }
    int ch = (m4 >> 1) ^ ((n >> 3) & 7), hf = m4 & 1;
    *(uint2*)&T[n * 64 + ch * 8 + hf * 4] = pk.v;
  }
  __syncthreads();
#pragma unroll
  for (int j = 0; j < 2; ++j) {
    int u = j * 256 + t;
    int om = u >> 3, nc = u & 7;
    Pk8 pk;
#pragma unroll
    for (int i = 0; i < 8; ++i) {
      int n = nc * 8 + i;
      int ch = (om >> 3) ^ ((n >> 3) & 7);
      pk.p[i] = T[n * 64 + ch * 8 + (om & 7)];
    }
    *(uint4*)(dst + (z * C + cBase + om) * R + rBase + nc * 8) = pk.v;
  }
}

// ------------- elementwise exp: E[i] = bf16(exp(s*cost[i])) --------------
__global__ __launch_bounds__(256) void eexp(const float* __restrict__ src,
                                            u16* __restrict__ dst, long n8,
                                            const float* __restrict__ al,
                                            int pi, const float* __restrict__ ls) {
  const float s = -al[pi] * ls[0];
  for (long i = blockIdx.x * 256 + threadIdx.x; i < n8;
       i += (long)gridDim.x * 256) {
    const float* p = src + i * 8;
    float4 v0 = *(const float4*)p, v1 = *(const float4*)(p + 4);
    Pk8 pk;
    pk.p[0] = f2bf(__expf(s * v0.x)); pk.p[1] = f2bf(__expf(s * v0.y));
    pk.p[2] = f2bf(__expf(s * v0.z)); pk.p[3] = f2bf(__expf(s * v0.w));
    pk.p[4] = f2bf(__expf(s * v1.x)); pk.p[5] = f2bf(__expf(s * v1.y));
    pk.p[6] = f2bf(__expf(s * v1.z)); pk.p[7] = f2bf(__expf(s * v1.w));
    *(uint4*)(dst + i * 8) = pk.v;
  }
}

// ------------- elementwise fp32 -> bf16 ----------------------------------
__global__ __launch_bounds__(256) void cvtb(const float* __restrict__ src,
                                            u16* __restrict__ dst, long n8) {
  for (long i = blockIdx.x * 256 + threadIdx.x; i < n8;
       i += (long)gridDim.x * 256) {
    const float* p = src + i * 8;
    float4 v0 = *(const float4*)p, v1 = *(const float4*)(p + 4);
    Pk8 pk;
    pk.p[0] = f2bf(v0.x); pk.p[1] = f2bf(v0.y);
    pk.p[2] = f2bf(v0.z); pk.p[3] = f2bf(v0.w);
    pk.p[4] = f2bf(v1.x); pk.p[5] = f2bf(v1.y);
    pk.p[6] = f2bf(v1.z); pk.p[7] = f2bf(v1.w);
    *(uint4*)(dst + i * 8) = pk.v;
  }
}

// --------------- shared MFMA inner step (BK=64, 128x128 tile) -------------
DEVFUN void mfma_step(const u16* As, const u16* Bs, int wr, int wc, int lr,
                      int lhi, f32x4 acc[4][4]) {
#pragma unroll
  for (int ks = 0; ks < 2; ++ks) {
    short8 af[4], bfr[4];
#pragma unroll
    for (int m = 0; m < 4; ++m) {
      int r = wr + m * 16 + lr;
      af[m] = *(const short8*)&As[r * 64 + (((ks << 2) + lhi) ^ (r & 7)) * 8];
    }
#pragma unroll
    for (int n = 0; n < 4; ++n) {
      int r = wc + n * 16 + lr;
      bfr[n] = *(const short8*)&Bs[r * 64 + (((ks << 2) + lhi) ^ (r & 7)) * 8];
    }
#pragma unroll
    for (int m = 0; m < 4; ++m)
#pragma unroll
      for (int n = 0; n < 4; ++n)
        acc[m][n] = __builtin_amdgcn_mfma_f32_16x16x32_bf16(af[m], bfr[n],
                                                            acc[m][n], 0, 0, 0);
  }
}

enum Epi { EP_SIG = 0, EP_RELUB, EP_BIASRES };

// C[65536 x NC] = A[65536 x K](bf16) @ WT[NC x K]^T(bf16); gload_lds staging
template <int EPI>
__global__ __launch_bounds__(256) void gemm_mf(
    const u16* __restrict__ Asrc, const u16* __restrict__ WT, int K, int gx,
    void* __restrict__ outp, const void* __restrict__ aux,
    const float* __restrict__ aux2) {
  __shared__ u16 As[128 * 64];
  __shared__ u16 Bs[128 * 64];
  const int t = threadIdx.x;
  const int lane = t & 63, wid = t >> 6;
  const int lr = lane & 15, lhi = lane >> 4;
  const int wr = (wid >> 1) * 64, wc = (wid & 1) * 64;
  const int cpx = gridDim.x >> 3;
  const int rb = (blockIdx.x & 7) * cpx + (blockIdx.x >> 3);
  const int bx = rb % gx;
  const long rowBase = (long)(rb / gx) * 128;
  const int colBase = bx * 128;
  const int r0 = wid * 32;
  const int rl = lane >> 3;            // 0..7 row within 8-row chunk
  const int sl = lane & 7;             // LDS chunk slot

  f32x4 acc[4][4];
#pragma unroll
  for (int m = 0; m < 4; ++m)
#pragma unroll
    for (int n = 0; n < 4; ++n) acc[m][n] = {0.f, 0.f, 0.f, 0.f};

  for (int kt = 0; kt < K; kt += 64) {
#pragma unroll
    for (int j = 0; j < 4; ++j) {
      int r = r0 + j * 8 + rl;
      int gch = sl ^ (r & 7);
      gload16(Asrc + (rowBase + r) * K + kt + gch * 8, &As[(r0 + j * 8) * 64]);
      gload16(WT + (long)(colBase + r) * K + kt + gch * 8,
              &Bs[(r0 + j * 8) * 64]);
    }
    __syncthreads();
    mfma_step(As, Bs, wr, wc, lr, lhi, acc);
    __syncthreads();
  }

#pragma unroll
  for (int m = 0; m < 4; ++m) {
#pragma unroll
    for (int n = 0; n < 4; ++n) {
#pragma unroll
      for (int rr = 0; rr < 4; ++rr) {
        float v = acc[m][n][rr];
        long grow = rowBase + wr + m * 16 + lhi * 4 + rr;
        int gcol = colBase + wc + n * 16 + lr;
        if constexpr (EPI == EP_SIG) {
          ((u16*)outp)[grow * 256 + gcol] = f2bf(fsig(v));
        } else if constexpr (EPI == EP_RELUB) {
          float bb = ((const float*)aux)[gcol];
          ((u16*)outp)[grow * 512 + gcol] = f2bf(fmaxf(v + bb, 0.f));
        } else {  // EP_BIASRES
          float bb = ((const float*)aux)[gcol];
          ((float*)outp)[grow * 256 + gcol] = v + bb + aux2[grow * 256 + gcol];
        }
      }
    }
  }
}

// ---- fused K/V GEMM: ek = exp(x@Wk), ekv = ek * (x@Wv), both written
// transposed+coalesced into CbufT ([b][d][m] ekv ; [b][256+d][m] ek).
union KvSm {
  struct { u16 A[128 * 64]; u16 Bk[128 * 64]; u16 Bv[128 * 64]; } s;  // 48KB
  u16 T[128 * 128];  // 32KB transpose staging
};

__global__ __launch_bounds__(256) void kv_mf(const u16* __restrict__ Asrc,
                                             const u16* __restrict__ WkT,
                                             const u16* __restrict__ WvT,
                                             u16* __restrict__ Cb) {
  __shared__ KvSm sm;
  const int t = threadIdx.x;
  const int lane = t & 63, wid = t >> 6;
  const int lr = lane & 15, lhi = lane >> 4;
  const int wr = (wid >> 1) * 64, wc = (wid & 1) * 64;
  const int cpx = gridDim.x >> 3;
  const int rb = (blockIdx.x & 7) * cpx + (blockIdx.x >> 3);
  const long rowBase = (long)(rb >> 1) * 128;
  const int colBase = (rb & 1) * 128;
  const long b = rowBase >> 9;
  const int mInB = (int)(rowBase & 511);
  const int r0 = wid * 32;
  const int rl = lane >> 3, sl = lane & 7;

  f32x4 ka[4][4], va[4][4];
#pragma unroll
  for (int m = 0; m < 4; ++m)
#pragma unroll
    for (int n = 0; n < 4; ++n) {
      ka[m][n] = {0.f, 0.f, 0.f, 0.f};
      va[m][n] = {0.f, 0.f, 0.f, 0.f};
    }

  for (int kt = 0; kt < 256; kt += 64) {
#pragma unroll
    for (int j = 0; j < 4; ++j) {
      int r = r0 + j * 8 + rl;
      int gch = sl ^ (r & 7);
      gload16(Asrc + (rowBase + r) * 256 + kt + gch * 8,
              &sm.s.A[(r0 + j * 8) * 64]);
      gload16(WkT + (long)(colBase + r) * 256 + kt + gch * 8,
              &sm.s.Bk[(r0 + j * 8) * 64]);
      gload16(WvT + (long)(colBase + r) * 256 + kt + gch * 8,
              &sm.s.Bv[(r0 + j * 8) * 64]);
    }
    __syncthreads();
    mfma_step(sm.s.A, sm.s.Bk, wr, wc, lr, lhi, ka);
    mfma_step(sm.s.A, sm.s.Bv, wr, wc, lr, lhi, va);
    __syncthreads();
  }

  // two transpose passes: pass0 = ek, pass1 = ekv = ek*v
#pragma unroll
  for (int pass = 0; pass < 2; ++pass) {
#pragma unroll
    for (int m = 0; m < 4; ++m) {
#pragma unroll
      for (int n = 0; n < 4; ++n) {
        int m0 = wr + m * 16 + lhi * 4;
        int d = wc + n * 16 + lr;
        Pk4 pk;
#pragma unroll
        for (int rr = 0; rr < 4; ++rr) {
          float ek = __expf(ka[m][n][rr]);
          pk.p[rr] = f2bf(pass ? ek * va[m][n][rr] : ek);
        }
        int slot = (m0 >> 3) ^ (d & 7);
        *(uint2*)&sm.T[d * 128 + slot * 8 + (m0 & 7)] = pk.v;
      }
    }
    __syncthreads();
    const long rbase = b * 512 + (pass ? 0 : 256) + colBase;
#pragma unroll
    for (int j = 0; j < 8; ++j) {
      int idx = j * 256 + t;
      int d = idx >> 4, c = idx & 15;
      uint4 v = *(const uint4*)&sm.T[d * 128 + ((c ^ (d & 7)) * 8)];
      *(uint4*)(Cb + (rbase + d) * 512 + mInB + c * 8) = v;
    }
    __syncthreads();
  }
}

// ---- fused AFT: num & den.  B rows 0..63 = ekv_t, 64..127 = ek_t ----
union SmU {
  struct { u16 A[128 * 64]; u16 B[128 * 64]; } s;
  float den[128 * 68];
};

__global__ __launch_bounds__(256) void aft_mf(
    const u16* __restrict__ Ebuf, const u16* __restrict__ CbufT,
    const u16* __restrict__ qb, const float* __restrict__ xr,
    float* __restrict__ dst) {
  __shared__ SmU sm;
  const int t = threadIdx.x;
  const int lane = t & 63, wid = t >> 6;
  const int lr = lane & 15, lhi = lane >> 4;
  const int wr = (wid >> 1) * 64, wc = (wid & 1) * 64;
  const int rb = (blockIdx.x & 7) * 256 + (blockIdx.x >> 3);
  const long b = rb >> 4;
  const int nBase = ((rb >> 2) & 3) * 128;
  const int dBase = (rb & 3) * 64;
  const int r0 = wid * 32;
  const int rl = lane >> 3, sl = lane & 7;

  f32x4 acc[4][4];
#pragma unroll
  for (int m = 0; m < 4; ++m)
#pragma unroll
    for (int n = 0; n < 4; ++n) acc[m][n] = {0.f, 0.f, 0.f, 0.f};

  for (int kt = 0; kt < 512; kt += 64) {
#pragma unroll
    for (int j = 0; j < 4; ++j) {
      int r = r0 + j * 8 + rl;
      int gch = sl ^ (r & 7);
      gload16(Ebuf + (b * 512 + nBase + r) * 512 + kt + gch * 8,
              &sm.s.A[(r0 + j * 8) * 64]);
      int gslot = (r < 64) ? (dBase + r) : (256 + dBase + (r - 64));
      gload16(CbufT + (b * 512 + gslot) * 512 + kt + gch * 8,
              &sm.s.B[(r0 + j * 8) * 64]);
    }
    __syncthreads();
    mfma_step(sm.s.A, sm.s.B, wr, wc, lr, lhi, acc);
    __syncthreads();
  }

  if (wc == 64) {  // den waves -> LDS
#pragma unroll
    for (int m = 0; m < 4; ++m)
#pragma unroll
      for (int n = 0; n < 4; ++n)
#pragma unroll
        for (int rr = 0; rr < 4; ++rr) {
          int nl = wr + m * 16 + lhi * 4 + rr;
          int dl = n * 16 + lr;
          sm.den[nl * 68 + dl] = acc[m][n][rr];
        }
  }
  __syncthreads();
  if (wc == 0) {  // num waves: combine + epilogue
#pragma unroll
    for (int m = 0; m < 4; ++m)
#pragma unroll
      for (int n = 0; n < 4; ++n)
#pragma unroll
        for (int rr = 0; rr < 4; ++rr) {
          int nl = wr + m * 16 + lhi * 4 + rr;
          int dl = n * 16 + lr;
          float dv = sm.den[nl * 68 + dl];
          float w = acc[m][n][rr] / dv;
          if (!(w == w)) w = 0.f;
          else if (w > 3.402823466e38f) w = 3.402823466e38f;
          else if (w < -3.402823466e38f) w = -3.402823466e38f;
          long grow = b * 512 + nBase + nl;
          int gcol = dBase + dl;
          float sq = bf2f(qb[grow * 256 + gcol]);
          dst[grow * 256 + gcol] = xr[grow * 256 + gcol] + sq * w;
        }
  }
}

// ----- instance norm over seq; in-place fp32 + bf16 copy -----------------
__global__ __launch_bounds__(256) void inorm(float* __restrict__ X,
                                             const float* __restrict__ g,
                                             const float* __restrict__ be,
                                             u16* __restrict__ Xb) {
  const int b = blockIdx.x;
  const int ch0 = blockIdx.y * 64;
  const int t = threadIdx.x;
  const int lc = t & 63;
  const int ch = ch0 + lc;
  const int nr = t >> 6;
  const long base = (long)b * kN * kD + ch;

  float sum = 0.f, sq = 0.f;
  for (int n = nr; n < kN; n += 4) {
    float x = X[base + (long)n * kD];
    sum += x;
    sq += x * x;
  }
  __shared__ float s1[4][64], s2[4][64];
  __shared__ float mu[64], rs[64], gg[64], bb[64];
  s1[nr][lc] = sum;
  s2[nr][lc] = sq;
  __syncthreads();
  if (t < 64) {
    float ssum = s1[0][t] + s1[1][t] + s1[2][t] + s1[3][t];
    float ssq = s2[0][t] + s2[1][t] + s2[2][t] + s2[3][t];
    float m = ssum * (1.f / kN);
    float v = ssq * (1.f / kN) - m * m;
    mu[t] = m;
    rs[t] = rsqrtf(v + kEPS);
    gg[t] = g[ch0 + t];
    bb[t] = be[ch0 + t];
  }
  __syncthreads();
  const float m = mu[lc], rr = rs[lc], G = gg[lc], Bt = bb[lc];
  for (int n = nr; n < kN; n += 4) {
    long idx = base + (long)n * kD;
    float y = (X[idx] - m) * rr * G + Bt;
    X[idx] = y;
    Xb[idx] = f2bf(y);
  }
}

}  // namespace

extern "C" void kernel_launch(void* const* d_in, const int* in_sizes, int n_in,
                              void* d_out, int out_size, void* d_ws,
                              size_t ws_size, hipStream_t stream) {
  (void)in_sizes; (void)n_in; (void)out_size; (void)ws_size;

  const float* in_row = (const float*)d_in[0];
  const float* in_col = (const float*)d_in[1];
  const float* cost = (const float*)d_in[2];
  const float* lsc = (const float*)d_in[3];
  const float* Wq = (const float*)d_in[4];
  const float* Wk = (const float*)d_in[5];
  const float* Wv = (const float*)d_in[6];
  const float* g1 = (const float*)d_in[7];
  const float* be1 = (const float*)d_in[8];
  const float* W1 = (const float*)d_in[9];
  const float* b1 = (const float*)d_in[10];
  const float* W2 = (const float*)d_in[11];
  const float* b2 = (const float*)d_in[12];
  const float* g2 = (const float*)d_in[13];
  const float* be2 = (const float*)d_in[14];
  const float* alpha = (const float*)d_in[15];

  float* outRow = (float*)d_out;
  float* outCol = outRow + BND;
  float* ppRow = (float*)d_ws;          // BND f32
  float* ppCol = ppRow + BND;           // BND f32
  u16* qb = (u16*)(ppCol + BND);        // BND bf16 (sigmoid q; aliased as h1b)
  u16* h1b = qb;
  u16* CbufT = qb + BND;                // 2*BND bf16
  u16* ffmid = CbufT;                   // alias (dead after AFT)
  u16* Ebuf = CbufT + 2 * BND;          // 2*BND bf16: exp(s*cost) per side
  u16* bSt = Ebuf + 2 * BND;            // 4*BND bf16 states [parity][side]
  u16* WqT = bSt + 4 * BND;
  u16* WkT = WqT + 10L * 256 * 256;
  u16* WvT = WkT + 10L * 256 * 256;
  u16* W1T = WvT + 10L * 256 * 256;     // [pi][f=512][d=256]
  u16* W2T = W1T + 10L * 512 * 256;     // [pi][d=256][f=512]

  const dim3 blk(256);
  // one-time prep
  tcvt<false><<<dim3(4, 4, 10), blk, 0, stream>>>(Wq, WqT, 256, 256, nullptr, 0, nullptr);
  tcvt<false><<<dim3(4, 4, 10), blk, 0, stream>>>(Wk, WkT, 256, 256, nullptr, 0, nullptr);
  tcvt<false><<<dim3(4, 4, 10), blk, 0, stream>>>(Wv, WvT, 256, 256, nullptr, 0, nullptr);
  tcvt<false><<<dim3(8, 4, 10), blk, 0, stream>>>(W1, W1T, 256, 512, nullptr, 0, nullptr);
  tcvt<false><<<dim3(4, 8, 10), blk, 0, stream>>>(W2, W2T, 512, 256, nullptr, 0, nullptr);
  cvtb<<<1024, blk, 0, stream>>>(in_row, bSt + 0 * BND, BND / 8);
  cvtb<<<1024, blk, 0, stream>>>(in_col, bSt + 1 * BND, BND / 8);

  for (int l = 0; l < kL; ++l) {
    const int inPar = l & 1, outPar = 1 - inPar;
    const float* srcR = (l == 0) ? in_row
                                 : (inPar ? (const float*)outRow
                                          : (const float*)ppRow);
    const float* srcC = (l == 0) ? in_col
                                 : (inPar ? (const float*)outCol
                                          : (const float*)ppCol);
    float* dstR = inPar ? ppRow : outRow;
    float* dstC = inPar ? ppCol : outCol;
    const u16* bR = bSt + (inPar * 2 + 0) * BND;
    const u16* bC = bSt + (inPar * 2 + 1) * BND;

    for (int side = 0; side < 2; ++side) {
      const float* xr = side ? srcC : srcR;
      const u16* xrB = side ? bC : bR;
      const u16* xcB = side ? bR : bC;
      float* dst = side ? dstC : dstR;
      u16* outB = bSt + (outPar * 2 + side) * BND;
      const int pi = l * 2 + side;

      // E = bf16(exp(-alpha*lsc * cost)), oriented for this side's rows
      if (side == 0)
        eexp<<<4096, blk, 0, stream>>>(cost, Ebuf, (long)kB * 512 * 512 / 8,
                                       alpha, pi, lsc);
      else
        tcvt<true><<<dim3(8, 8, 128), blk, 0, stream>>>(cost, Ebuf, 512, 512,
                                                        alpha, pi, lsc);

      gemm_mf<EP_SIG><<<1024, blk, 0, stream>>>(
          xrB, WqT + (long)pi * 256 * 256, 256, 2, qb, nullptr, nullptr);
      kv_mf<<<1024, blk, 0, stream>>>(xcB, WkT + (long)pi * 256 * 256,
                                      WvT + (long)pi * 256 * 256, CbufT);
      aft_mf<<<2048, blk, 0, stream>>>(Ebuf, CbufT, qb, xr, dst);
      inorm<<<dim3(128, 4), blk, 0, stream>>>(dst, g1 + pi * 256,
                                              be1 + pi * 256, h1b);
      gemm_mf<EP_RELUB><<<2048, blk, 0, stream>>>(
          h1b, W1T + (long)pi * 512 * 256, 256, 4, ffmid, b1 + pi * 512,
          nullptr);
      gemm_mf<EP_BIASRES><<<1024, blk, 0, stream>>>(
          ffmid, W2T + (long)pi * 256 * 512, 512, 2, dst, b2 + pi * 256, dst);
      inorm<<<dim3(128, 4), blk, 0, stream>>>(dst, g2 + pi * 256,
                                              be2 + pi * 256, outB);
    }
  }
}